// Round 16
// baseline (3141.895 us; speedup 1.0000x reference)
//
#include <hip/hip_runtime.h>

#define B 64
#define S 128
#define T 64
#define H 512
#define E 256
#define V 10000
#define H2 1024      // 2H
#define G4 2048      // 4H
#define KX 1536      // ctx(1024)+h(512) gate GEMM K
#define KP 1792      // E + H + 2H pre concat K
#define VP 10112     // padded V = 79*128
#define NROW 4096    // B*T

typedef unsigned short u16;
typedef __attribute__((ext_vector_type(8))) short bf16x8;
typedef __attribute__((ext_vector_type(4))) short bf16x4;
typedef __attribute__((ext_vector_type(4))) float floatx4;

__device__ inline float b2f(u16 h){
  union { unsigned int u; float f; } v; v.u = ((unsigned int)h) << 16; return v.f;
}
__device__ inline u16 f2b(float f){
  union { unsigned int u; float f; } v; v.f = f;
  unsigned int r = v.u + 0x7FFFu + ((v.u >> 16) & 1u);
  return (u16)(r >> 16);
}
__device__ __forceinline__ float rcpf(float x){ return __builtin_amdgcn_rcpf(x); }
__device__ inline float sigf(float x){ return rcpf(1.f + __expf(-x)); }
__device__ inline float tanh_fast(float x){ float e=__expf(2.f*x); return 1.f - 2.f*rcpf(e+1.f); }

// ---- IF$-coherent ops (sc0 sc1): the ONLY proven cross-CU-coherent path (R4/R6/R9; R7: sc0-only fails) ----
__device__ __forceinline__ void st_wt_u32(u16* p, unsigned v){
  asm volatile("global_store_dword %0, %1, off sc0 sc1" :: "v"(p), "v"(v) : "memory");
}
__device__ __forceinline__ void st_wt_u16(u16* p, unsigned v){
  asm volatile("global_store_short %0, %1, off sc0 sc1" :: "v"(p), "v"(v) : "memory");
}
__device__ __forceinline__ unsigned ld_if(unsigned* p){
  unsigned v;
  asm volatile("global_load_dword %0, %1, off sc0 sc1\ns_waitcnt vmcnt(0)" : "=v"(v) : "v"(p) : "memory");
  return v;
}
__device__ __forceinline__ void st_if(unsigned* p, unsigned v){
  asm volatile("global_store_dword %0, %1, off sc0 sc1\ns_waitcnt vmcnt(0)" :: "v"(p), "v"(v) : "memory");
}

#define BAR_WORDS (128*64)

// ---------------- prep kernels ----------------
__global__ void k_cast(const float* __restrict__ src, u16* __restrict__ dst, int n){
  int i = blockIdx.x*256 + threadIdx.x;
  if (i < n) dst[i] = f2b(src[i]);
}
__global__ void k_tct(const float* __restrict__ src, u16* __restrict__ dst, int R, int C){
  __shared__ float tile[64][65];
  int c0 = blockIdx.x*64, r0 = blockIdx.y*64;
  int tid = threadIdx.x;
  #pragma unroll
  for (int i=0;i<16;i++){
    int flat = i*256 + tid;
    int rr = flat >> 6, cc = flat & 63;
    int c = c0 + cc;
    tile[rr][cc] = (c < C) ? src[(size_t)(r0+rr)*C + c] : 0.f;
  }
  __syncthreads();
  #pragma unroll
  for (int i=0;i<16;i++){
    int flat = i*256 + tid;
    int cc = flat >> 6, rr = flat & 63;
    dst[(size_t)(c0+cc)*R + r0 + rr] = f2b(tile[rr][cc]);
  }
}
// encbT[b][d][s] = enc[b][s][d] (bf16)
__global__ void k_encT(const float* __restrict__ enc, u16* __restrict__ o){
  __shared__ float tile[64][65];
  int d0 = blockIdx.x*64, s0 = blockIdx.y*64, b = blockIdx.z;
  int tid = threadIdx.x;
  #pragma unroll
  for (int i=0;i<16;i++){
    int flat = i*256 + tid;
    int sl = flat >> 6, dl = flat & 63;
    tile[sl][dl] = enc[((size_t)(b*S) + s0+sl)*H2 + d0+dl];
  }
  __syncthreads();
  #pragma unroll
  for (int i=0;i<16;i++){
    int flat = i*256 + tid;
    int dl = flat >> 6, sl = flat & 63;
    o[((size_t)b*H2 + d0+dl)*S + s0+sl] = f2b(tile[sl][dl]);
  }
}
__global__ void k_wch(const float* __restrict__ wih, const float* __restrict__ whh, u16* __restrict__ o){
  int i = blockIdx.x*256 + threadIdx.x;
  if (i < G4*KX){
    int gp = i / KX, k = i % KX;
    int j = gp >> 2, gate = gp & 3, g = gate*H + j;
    float v = (k < H2) ? wih[(size_t)g*(E+H2) + E + k] : whh[(size_t)g*H + (k - H2)];
    o[i] = f2b(v);
  }
}
__global__ void k_wihe(const float* __restrict__ wih, u16* __restrict__ o){
  int i = blockIdx.x*256 + threadIdx.x;
  if (i < G4*E){
    int gp = i / E, e = i % E;
    int j = gp >> 2, gate = gp & 3, g = gate*H + j;
    o[i] = f2b(wih[(size_t)g*(E+H2) + e]);
  }
}
__global__ void k_bias(const float* __restrict__ bi, const float* __restrict__ bh, float* __restrict__ o){
  int i = blockIdx.x*256 + threadIdx.x;
  if (i < G4){
    int j = i >> 2, gate = i & 3, g = gate*H + j;
    o[i] = bi[g] + bh[g];
  }
}
__global__ void k_emb(const int* __restrict__ trg, const float* __restrict__ emb, u16* __restrict__ catp){
  int i = blockIdx.x*256 + threadIdx.x;
  if (i < NROW*E){
    int row = i >> 8, e = i & 255;
    int tok = trg[row];
    catp[(size_t)row*KP + e] = f2b(emb[(size_t)tok*E + e]);
  }
}
__global__ void k_init(const float* __restrict__ h0, u16* __restrict__ xgs){
  int i = blockIdx.x*256 + threadIdx.x;
  if (i < B*H){
    int b = i >> 9, j = i & 511;
    xgs[(size_t)b*KX + H2 + j] = f2b(h0[i]);   // slot 0 h-region
  }
}
__global__ void k_zero(unsigned* bar){
  int i = blockIdx.x*256 + threadIdx.x;
  if (i < BAR_WORDS) bar[i] = 0u;
}
__global__ void k_lse(const float* __restrict__ sep, float* __restrict__ lse){
  int r = blockIdx.x*256 + threadIdx.x;
  if (r < NROW){
    float s = 0.f;
    for (int i=0;i<79;i++) s += sep[(size_t)r*80 + i];
    lse[r] = logf(s);
  }
}

// ---------------- MFMA GEMM: C[row,col] = sum_k A[row,k]*BT[col,k] ----------------
template<int TN, int EPI>
__global__ __launch_bounds__(256) void gemm_bf16(
    const u16* __restrict__ A, int lda,
    const u16* __restrict__ BT, int ldb,
    int K,
    u16* outb, int ldc,
    float* sep,
    float* outp, const float* lse)
{
  constexpr int NSUB = TN/16;
  constexpr int NB = TN/64;
  __shared__ u16 sA[64*32];
  __shared__ u16 sB[TN*32];
  __shared__ float Cx[(EPI==3) ? 128*65 : 1];
  __shared__ float lseb[(EPI==3)?64:1];

  const int tid = threadIdx.x;
  const int lane = tid & 63;
  const int wv = tid >> 6;
  const int row0 = blockIdx.x * 64;
  const int n0 = blockIdx.y * TN;

  floatx4 acc[NSUB];
  #pragma unroll
  for (int s=0;s<NSUB;s++) acc[s] = (floatx4){0.f,0.f,0.f,0.f};

  const int ar = tid >> 2;
  const int ch = tid & 3;
  const int swz = (ar >> 1) & 3;
  const int px = ((lane & 15) >> 1) & 3;

  const u16* gA = A + (size_t)(row0+ar)*lda + ch*8;
  bf16x8 pa = *(const bf16x8*)gA;
  bf16x8 pb[NB];
  #pragma unroll
  for (int i=0;i<NB;i++) pb[i] = *(const bf16x8*)(BT + (size_t)(n0+i*64+ar)*ldb + ch*8);

  for (int k0 = 0; k0 < K; k0 += 32){
    __syncthreads();
    *(bf16x8*)&sA[ar*32 + ((ch ^ swz)*8)] = pa;
    #pragma unroll
    for (int i=0;i<NB;i++)
      *(bf16x8*)&sB[(i*64+ar)*32 + ((ch ^ swz)*8)] = pb[i];
    __syncthreads();
    if (k0 + 32 < K){
      pa = *(const bf16x8*)(gA + k0 + 32);
      #pragma unroll
      for (int i=0;i<NB;i++) pb[i] = *(const bf16x8*)(BT + (size_t)(n0+i*64+ar)*ldb + k0+32 + ch*8);
    }
    bf16x8 af = *(const bf16x8*)&sA[(16*wv + (lane&15))*32 + (((lane>>4) ^ px)*8)];
    #pragma unroll
    for (int s=0;s<NSUB;s++){
      bf16x8 bfv = *(const bf16x8*)&sB[(16*s + (lane&15))*32 + (((lane>>4) ^ px)*8)];
      acc[s] = __builtin_amdgcn_mfma_f32_16x16x32_bf16(af, bfv, acc[s], 0, 0, 0);
    }
  }

  if constexpr (EPI == 0 || EPI == 4){
    #pragma unroll
    for (int s=0;s<NSUB;s++)
      #pragma unroll
      for (int r=0;r<4;r++){
        int row = row0 + 16*wv + ((lane>>4)<<2) + r;
        int col = n0 + 16*s + (lane&15);
        if (EPI == 4) row = ((row & 63) << 6) | (row >> 6);   // b*T+t -> t*B+b
        outb[(size_t)row*ldc + col] = f2b(acc[s][r]);
      }
  }
  if constexpr (EPI == 2){
    float sr[4] = {0.f,0.f,0.f,0.f};
    #pragma unroll
    for (int s=0;s<NSUB;s++){
      int col = n0 + 16*s + (lane&15);
      if (col < V){
        #pragma unroll
        for (int r=0;r<4;r++) sr[r] += __expf(acc[s][r]);
      }
    }
    #pragma unroll
    for (int r=0;r<4;r++){
      float v = sr[r];
      v += __shfl_xor(v,1); v += __shfl_xor(v,2); v += __shfl_xor(v,4); v += __shfl_xor(v,8);
      sr[r] = v;
    }
    if ((lane&15)==0){
      #pragma unroll
      for (int r=0;r<4;r++){
        int row = row0 + 16*wv + ((lane>>4)<<2) + r;
        sep[(size_t)row*80 + blockIdx.y] = sr[r];
      }
    }
  }
  if constexpr (EPI == 3){
    #pragma unroll
    for (int s=0;s<NSUB;s++)
      #pragma unroll
      for (int r=0;r<4;r++){
        int rl = 16*wv + ((lane>>4)<<2) + r;
        int cl = 16*s + (lane&15);
        Cx[cl*65 + rl] = acc[s][r];
      }
    if (tid < 64) lseb[tid] = lse[row0 + tid];
    __syncthreads();
    int b = blockIdx.x;
    for (int idx = tid; idx < TN*16; idx += 256){
      int vl = idx >> 4, q4 = idx & 15;
      int v = n0 + vl;
      if (v < V){
        floatx4 o;
        o[0] = Cx[vl*65 + q4*4+0] - lseb[q4*4+0];
        o[1] = Cx[vl*65 + q4*4+1] - lseb[q4*4+1];
        o[2] = Cx[vl*65 + q4*4+2] - lseb[q4*4+2];
        o[3] = Cx[vl*65 + q4*4+3] - lseb[q4*4+3];
        *(floatx4*)&outp[((size_t)b*V + v)*T + q4*4] = o;
      }
    }
  }
}

// ---------------- gentle producer->consumer flag wait (64 lines) ----------------
__device__ __forceinline__ void wait_flags(unsigned* base, unsigned g){
  if (threadIdx.x < 64){
    unsigned* p = base + (unsigned)threadIdx.x*64;
    if (ld_if(p) < g){
      int it = 0;
      do { asm volatile("s_sleep 1":::); } while (ld_if(p) < g && ++it < 4000000);
    }
  }
  __syncthreads();
}

// ---------------- persistent recurrence: 128 blocks x 512 threads, split roles ----------------
// attn blocks 0..63; gates blocks 64..127 (32-col slice, split-K 8 waves).
// R16: forced burst loads (sched_barrier + single vmcnt drain) for gates A-fragments and attn
//      q h-fragments; B persistent in LDS (R13-proven).
__global__ __launch_bounds__(512) void decoder_loop(
    u16* __restrict__ xgs, const float* __restrict__ c0f, float* __restrict__ outp,
    const u16* __restrict__ pk, const u16* __restrict__ encbT,
    const float* __restrict__ we, const int* __restrict__ lens,
    const u16* __restrict__ wqT, u16* __restrict__ cph,
    const u16* __restrict__ wch, const u16* __restrict__ gembt,
    const float* __restrict__ bias, unsigned* __restrict__ bar)
{
  __shared__ char pool[107520];

  const int tid = threadIdx.x, lane = tid & 63, wv = tid >> 6;
  const int blk = blockIdx.x;
  const int xcd = blk & 7, slot = blk >> 3;
  unsigned* flag_ctx = bar;            // [b]
  unsigned* flag_h   = bar + 64*64;    // [g]

  if (slot < 8){
    // ================= attention role (blocks 0..63) =================
    float* qw   = (float*)(pool + 1024);      // [512]
    float* wel  = (float*)(pool + 3072);      // [512]
    float* ep   = (float*)(pool + 5120);      // [512]
    u16*   alb  = (u16*)(pool + 7680);        // [128]
    float* ctxf = (float*)(pool + 8192);      // [1024]

    const int b = xcd*8 + slot;
    const int lenb = lens[b];
    const int nks = (lenb + 31) >> 5;
    wel[tid] = we[tid];
    __syncthreads();

    for (int t=0; t<T; t++){
      wait_flags(flag_h, (unsigned)t);
      u16* xgt = xgs + (size_t)t*B*KX;

      // ===== q = h @ Wquery: h fragments register-direct (burst + single drain) =====
      {
        const u16* hBase = xgt + b*KX + H2 + (lane>>4)*8;
        bf16x8 ha[16];
        #pragma unroll
        for (int ks=0; ks<16; ks++) ha[ks] = *(const bf16x8*)(hBase + ks*32);
        __builtin_amdgcn_sched_barrier(0);
        asm volatile("s_waitcnt vmcnt(0)" ::: "memory");
        __builtin_amdgcn_sched_barrier(0);
        floatx4 accq[4];
        #pragma unroll
        for (int s=0;s<4;s++) accq[s] = (floatx4){0.f,0.f,0.f,0.f};
        const int kc = (lane>>4)*8;
        #pragma unroll 4
        for (int ks=0; ks<16; ks++){
          #pragma unroll
          for (int s=0;s<4;s++){
            const u16* bp = wqT + (size_t)(wv*64 + s*16 + (lane&15))*H + ks*32 + kc;
            accq[s] = __builtin_amdgcn_mfma_f32_16x16x32_bf16(ha[ks], *(const bf16x8*)bp, accq[s], 0, 0, 0);
          }
        }
        if (lane < 16){
          #pragma unroll
          for (int s=0;s<4;s++) qw[wv*64 + s*16 + lane] = accq[s][0];
        }
      }
      __syncthreads();
      // ===== energies (4 threads per s; skip s >= lenb) =====
      {
        int s = tid >> 2, part = tid & 3;
        float a0 = 0.f;
        if (s < lenb){
          const u16* pr = pk + (size_t)(b*S + s)*H;
          #pragma unroll 4
          for (int m=0;m<16;m++){
            int k0 = part*8 + m*32;
            bf16x8 p8 = *(const bf16x8*)(pr + k0);
            floatx4 qa = *(const floatx4*)&qw[k0];
            floatx4 qb = *(const floatx4*)&qw[k0+4];
            floatx4 wa = *(const floatx4*)&wel[k0];
            floatx4 wb = *(const floatx4*)&wel[k0+4];
            #pragma unroll
            for (int i=0;i<4;i++){
              a0 += tanh_fast(qa[i] + b2f((u16)p8[i]))   * wa[i];
              a0 += tanh_fast(qb[i] + b2f((u16)p8[i+4])) * wb[i];
            }
          }
        }
        ep[tid] = a0;
      }
      __syncthreads();
      // ===== softmax in wave 0 only =====
      if (wv == 0){
        int s0 = lane, s1 = lane + 64;
        float e0 = ep[s0*4]+ep[s0*4+1]+ep[s0*4+2]+ep[s0*4+3];
        float e1 = ep[s1*4]+ep[s1*4+1]+ep[s1*4+2]+ep[s1*4+3];
        bool m0 = s0 < lenb, m1 = s1 < lenb;
        float mx = fmaxf(m0 ? e0 : -1e30f, m1 ? e1 : -1e30f);
        #pragma unroll
        for (int o=32;o>=1;o>>=1) mx = fmaxf(mx, __shfl_xor(mx,o));
        float p0 = m0 ? __expf(e0-mx) : 0.f;
        float p1 = m1 ? __expf(e1-mx) : 0.f;
        float sm = p0 + p1;
        #pragma unroll
        for (int o=32;o>=1;o>>=1) sm += __shfl_xor(sm,o);
        float sinv = rcpf(sm);
        alb[s0] = f2b(p0*sinv);
        alb[s1] = f2b(p1*sinv);
      }
      __syncthreads();
      // ===== ctx = al @ enc via MFMA on encbT[b][d][s]; only s<lenb chunks =====
      {
        floatx4 accc[8];
        #pragma unroll
        for (int s=0;s<8;s++) accc[s] = (floatx4){0.f,0.f,0.f,0.f};
        const int kc = (lane>>4)*8;
        for (int ks=0; ks<nks; ks++){
          bf16x8 af = *(const bf16x8*)&alb[ks*32 + kc];
          #pragma unroll
          for (int s8=0;s8<8;s8++){
            const u16* bp = encbT + ((size_t)b*H2 + wv*128 + s8*16 + (lane&15))*S + ks*32 + kc;
            accc[s8] = __builtin_amdgcn_mfma_f32_16x16x32_bf16(af, *(const bf16x8*)bp, accc[s8], 0, 0, 0);
          }
        }
        if (lane < 16){
          #pragma unroll
          for (int s8=0;s8<8;s8++) ctxf[wv*128 + s8*16 + lane] = accc[s8][0];
        }
      }
      __syncthreads();
      // pack + publish ctx
      {
        int d = tid*2;
        unsigned pack = ((unsigned)f2b(ctxf[d+1]) << 16) | (unsigned)f2b(ctxf[d]);
        st_wt_u32(xgt + (size_t)b*KX + d, pack);
        *(unsigned*)&cph[(size_t)(b*T + t)*KP + E + H + d] = pack;
      }
      asm volatile("s_waitcnt vmcnt(0)" ::: "memory");
      __syncthreads();
      if (tid == 0) st_if(flag_ctx + (unsigned)b*64, (unsigned)(t+1));
      __syncthreads();
    }
  } else {
    // ================= gates role (blocks 64..127) =================
    // C[64 b x 32 cols], K=1536, split-K: kh=wv>>2 owns K-half, wr=wv&3 owns 16 rows.
    // A-fragments register-direct burst (forced with sched_barrier); B persistent LDS.
    u16*   sB  = (u16*)pool;                  // [32][1536] swizzled, persistent (96 KB)
    float* Cx  = (float*)(pool + 98304);      // [64][36]

    const int g = slot - 8;
    const int gid = xcd*8 + g;
    const int n0 = xcd*256 + g*32;
    const int kh = wv >> 2, wr = wv & 3;
    const int pb_ = tid >> 3, jl = tid & 7;
    const int jglob = n0/4 + jl;
    float creg = c0f[pb_*H + jglob];
    floatx4 bias4 = *(const floatx4*)(bias + n0 + jl*4);

    const int arow = 16*wr + (lane & 15);
    const int kq8  = (lane >> 4) * 8;
    const int rowb0 = (lane & 15);
    const int rowb1 = 16 + (lane & 15);

    // ---- fill persistent B tile once (swizzled) ----
    for (int u = tid; u < 32*192; u += 512){
      int row = u / 192, cl = u % 192;
      int kk = cl >> 4, c = cl & 15;
      *(bf16x8*)&sB[row*1536 + kk*128 + ((c ^ (row&7))*8)] =
          *(const bf16x8*)(wch + (size_t)(n0+row)*KX + kk*128 + c*8);
    }
    __syncthreads();

    for (int t=0; t<T; t++){
      const u16* xgt = xgs + (size_t)t*B*KX;
      u16* xgn = xgs + (size_t)(t+1)*B*KX;
      bf16x4 g4 = *(const bf16x4*)(gembt + (size_t)(t*B + pb_)*G4 + n0 + jl*4);

      // wait ctx(t), then burst-load ALL 24 A-fragments, force-drain, then MFMA
      wait_flags(flag_ctx, (unsigned)(t+1));
      const u16* aBase = xgt + (size_t)arow*KX + kh*768 + kq8;
      bf16x8 fa[24];
      #pragma unroll
      for (int c=0;c<24;c++) fa[c] = *(const bf16x8*)(aBase + c*32);
      __builtin_amdgcn_sched_barrier(0);
      asm volatile("s_waitcnt vmcnt(0)" ::: "memory");
      __builtin_amdgcn_sched_barrier(0);

      floatx4 gacc[2];
      gacc[0] = (floatx4){0.f,0.f,0.f,0.f};
      gacc[1] = (floatx4){0.f,0.f,0.f,0.f};
      #pragma unroll
      for (int c=0;c<24;c++){
        int kcb = kh*768 + c*32;
        int kk = kcb >> 7;
        int gq = ((kcb & 127) >> 3) + (lane >> 4);
        bf16x8 b0 = *(const bf16x8*)&sB[rowb0*1536 + kk*128 + ((gq ^ (rowb0&7))*8)];
        bf16x8 b1 = *(const bf16x8*)&sB[rowb1*1536 + kk*128 + ((gq ^ (rowb1&7))*8)];
        gacc[0] = __builtin_amdgcn_mfma_f32_16x16x32_bf16(fa[c], b0, gacc[0], 0, 0, 0);
        gacc[1] = __builtin_amdgcn_mfma_f32_16x16x32_bf16(fa[c], b1, gacc[1], 0, 0, 0);
      }

      // ---- combine split-K halves via Cx ----
      {
        int r0 = 16*wr + ((lane>>4)<<2);
        if (kh == 1){
          #pragma unroll
          for (int s=0;s<2;s++)
            #pragma unroll
            for (int r=0;r<4;r++) Cx[(r0+r)*36 + 16*s + (lane&15)] = gacc[s][r];
        }
      }
      __syncthreads();
      {
        int r0 = 16*wr + ((lane>>4)<<2);
        if (kh == 0){
          #pragma unroll
          for (int s=0;s<2;s++)
            #pragma unroll
            for (int r=0;r<4;r++) Cx[(r0+r)*36 + 16*s + (lane&15)] += gacc[s][r];
        }
      }
      __syncthreads();
      // ---- LSTM pointwise ----
      {
        float gi = Cx[pb_*36 + jl*4+0] + b2f((u16)g4[0]) + bias4[0];
        float gf = Cx[pb_*36 + jl*4+1] + b2f((u16)g4[1]) + bias4[1];
        float gg = Cx[pb_*36 + jl*4+2] + b2f((u16)g4[2]) + bias4[2];
        float go = Cx[pb_*36 + jl*4+3] + b2f((u16)g4[3]) + bias4[3];
        float cn = sigf(gf)*creg + sigf(gi)*tanh_fast(gg);
        float hn = sigf(go)*tanh_fast(cn);
        creg = cn;
        u16 hb = f2b(hn);
        st_wt_u16(xgn + (size_t)pb_*KX + H2 + jglob, (unsigned)hb);
        cph[(size_t)(pb_*T + t)*KP + E + jglob] = hb;
        if (t == T-1){
          outp[(size_t)B*V*T + pb_*H + jglob] = hn;
          outp[(size_t)B*V*T + B*H + pb_*H + jglob] = cn;
        }
      }
      asm volatile("s_waitcnt vmcnt(0)" ::: "memory");
      __syncthreads();
      if (tid == 0) st_if(flag_h + (unsigned)gid*64, (unsigned)(t+1));
      __syncthreads();
    }
  }
}

static inline int cdiv(int a, int b){ return (a + b - 1) / b; }

extern "C" void kernel_launch(void* const* d_in, const int* in_sizes, int n_in,
                              void* d_out, int out_size, void* d_ws, size_t ws_size,
                              hipStream_t stream)
{
  (void)in_sizes; (void)n_in; (void)out_size; (void)ws_size;
  const int*   trg  = (const int*)d_in[0];
  const float* enc  = (const float*)d_in[1];
  const int*   lens = (const int*)d_in[2];
  const float* h0   = (const float*)d_in[3];
  const float* c0   = (const float*)d_in[4];
  const float* embt = (const float*)d_in[5];
  const float* wkey = (const float*)d_in[6];
  const float* wqry = (const float*)d_in[7];
  const float* we   = (const float*)d_in[8];
  const float* wih  = (const float*)d_in[9];
  const float* whh  = (const float*)d_in[10];
  const float* bi   = (const float*)d_in[11];
  const float* bh   = (const float*)d_in[12];
  const float* wpre = (const float*)d_in[13];
  const float* wgen = (const float*)d_in[14];
  float* out = (float*)d_out;

  char* p = (char*)d_ws;
  auto carve = [&](size_t bytes)->char*{ char* r = p; p += (bytes + 255) & ~(size_t)255; return r; };
  u16*   encb  = (u16*)  carve((size_t)B*S*H2*2);
  u16*   encbT = (u16*)  carve((size_t)B*H2*S*2);
  u16*   pkb   = (u16*)  carve((size_t)B*S*H*2);
  u16*   catp  = (u16*)  carve((size_t)NROW*KP*2);
  u16*   gembb = (u16*)  carve((size_t)NROW*G4*2);   // [t*B+b][G4]
  u16*   preb  = (u16*)  carve((size_t)NROW*H*2);
  u16*   wgt   = (u16*)  carve((size_t)VP*H*2);
  u16*   wch   = (u16*)  carve((size_t)G4*KX*2);
  u16*   wihe  = (u16*)  carve((size_t)G4*E*2);
  u16*   wkeyT = (u16*)  carve((size_t)H*H2*2);
  u16*   wqT   = (u16*)  carve((size_t)H*H*2);
  u16*   wpreT = (u16*)  carve((size_t)H*KP*2);
  u16*   xgs   = (u16*)  carve((size_t)(T+1)*B*KX*2);  // 65 fresh slots
  float* biasp = (float*)carve((size_t)G4*4);
  float* sep   = (float*)carve((size_t)NROW*80*4);
  float* lse   = (float*)carve((size_t)NROW*4);
  unsigned* bar = (unsigned*)carve(BAR_WORDS*4);

  // ---- prep ----
  k_cast<<<cdiv(B*S*H2,256),256,0,stream>>>(enc, encb, B*S*H2);
  k_encT<<<dim3(H2/64, S/64, B),256,0,stream>>>(enc, encbT);
  k_tct<<<dim3(H/64, H/64),256,0,stream>>>(wqry, wqT, H, H);         // -> [H][H] (j,k)
  k_tct<<<dim3(H/64, H2/64),256,0,stream>>>(wkey, wkeyT, H2, H);     // -> [H][H2]
  k_tct<<<dim3(H/64, KP/64),256,0,stream>>>(wpre, wpreT, KP, H);     // -> [H][KP]
  k_tct<<<dim3(VP/64, H/64),256,0,stream>>>(wgen, wgt, H, V);        // -> [VP][H]
  k_wch<<<cdiv(G4*KX,256),256,0,stream>>>(wih, whh, wch);
  k_wihe<<<cdiv(G4*E,256),256,0,stream>>>(wih, wihe);
  k_bias<<<cdiv(G4,256),256,0,stream>>>(bi, bh, biasp);
  k_emb<<<cdiv(NROW*E,256),256,0,stream>>>(trg, embt, catp);
  k_init<<<cdiv(B*H,256),256,0,stream>>>(h0, xgs);
  k_zero<<<cdiv(BAR_WORDS,256),256,0,stream>>>(bar);

  // proj_key = enc @ Wkey  -> pk bf16 [B*S][H]
  gemm_bf16<64,0><<<dim3(B*S/64, H/64),256,0,stream>>>(
      encb, H2, wkeyT, H2, H2, pkb, H, nullptr, nullptr, nullptr);
  // Gemb = emb @ W_ih[:, :E].T (permuted cols), rows remapped to [t*B+b]
  gemm_bf16<64,4><<<dim3(NROW/64, G4/64),256,0,stream>>>(
      catp, KP, wihe, E, E, gembb, G4, nullptr, nullptr, nullptr);

  // ---- recurrence: split-role persistent kernel, forced-burst A + persistent-B LDS ----
  decoder_loop<<<128,512,0,stream>>>(xgs, c0, out, pkb, encbT, we, lens,
                                     wqT, catp, wch, gembb, biasp, bar);

  // pre = cat_pre @ Wpre -> bf16 [NROW][H]
  gemm_bf16<64,0><<<dim3(NROW/64, H/64),256,0,stream>>>(
      catp, KP, wpreT, KP, KP, preb, H, nullptr, nullptr, nullptr);

  // generator pass 1: sum-exp partials
  gemm_bf16<128,2><<<dim3(NROW/64, VP/128),256,0,stream>>>(
      preb, H, wgt, H, H, nullptr, 0, sep, nullptr, nullptr);
  k_lse<<<cdiv(NROW,256),256,0,stream>>>(sep, lse);
  // generator pass 2: write out[b][v][t] = logit - lse
  gemm_bf16<128,3><<<dim3(NROW/64, VP/128),256,0,stream>>>(
      preb, H, wgt, H, H, nullptr, 0, nullptr, out, lse);
}

// Round 17
// 2499.062 us; speedup vs baseline: 1.2572x; 1.2572x over previous
//
#include <hip/hip_runtime.h>

#define B 64
#define S 128
#define T 64
#define H 512
#define E 256
#define V 10000
#define H2 1024      // 2H
#define G4 2048      // 4H
#define KX 1536      // ctx(1024)+h(512) gate GEMM K
#define KP 1792      // E + H + 2H pre concat K
#define VP 10112     // padded V = 79*128
#define NROW 4096    // B*T

typedef unsigned short u16;
typedef __attribute__((ext_vector_type(8))) short bf16x8;
typedef __attribute__((ext_vector_type(4))) short bf16x4;
typedef __attribute__((ext_vector_type(4))) float floatx4;

__device__ inline float b2f(u16 h){
  union { unsigned int u; float f; } v; v.u = ((unsigned int)h) << 16; return v.f;
}
__device__ inline u16 f2b(float f){
  union { unsigned int u; float f; } v; v.f = f;
  unsigned int r = v.u + 0x7FFFu + ((v.u >> 16) & 1u);
  return (u16)(r >> 16);
}
__device__ __forceinline__ float rcpf(float x){ return __builtin_amdgcn_rcpf(x); }
__device__ inline float sigf(float x){ return rcpf(1.f + __expf(-x)); }
__device__ inline float tanh_fast(float x){ float e=__expf(2.f*x); return 1.f - 2.f*rcpf(e+1.f); }

// ---- IF$-coherent ops (sc0 sc1): the ONLY proven cross-CU-coherent path (R4/R6/R9; R7: sc0-only fails) ----
__device__ __forceinline__ void st_wt_u32(u16* p, unsigned v){
  asm volatile("global_store_dword %0, %1, off sc0 sc1" :: "v"(p), "v"(v) : "memory");
}
__device__ __forceinline__ void st_wt_u16(u16* p, unsigned v){
  asm volatile("global_store_short %0, %1, off sc0 sc1" :: "v"(p), "v"(v) : "memory");
}
__device__ __forceinline__ unsigned ld_if(unsigned* p){
  unsigned v;
  asm volatile("global_load_dword %0, %1, off sc0 sc1\ns_waitcnt vmcnt(0)" : "=v"(v) : "v"(p) : "memory");
  return v;
}
__device__ __forceinline__ void st_if(unsigned* p, unsigned v){
  asm volatile("global_store_dword %0, %1, off sc0 sc1\ns_waitcnt vmcnt(0)" :: "v"(p), "v"(v) : "memory");
}

// flag layout: flag_ctx[b] at bar+b*64, flag_h[g] at bar+(64+g)*64 (256B-spaced lines)
#define BAR_WORDS (128*64)

// ---------------- prep kernels ----------------
__global__ void k_cast(const float* __restrict__ src, u16* __restrict__ dst, int n){
  int i = blockIdx.x*256 + threadIdx.x;
  if (i < n) dst[i] = f2b(src[i]);
}
__global__ void k_tct(const float* __restrict__ src, u16* __restrict__ dst, int R, int C){
  __shared__ float tile[64][65];
  int c0 = blockIdx.x*64, r0 = blockIdx.y*64;
  int tid = threadIdx.x;
  #pragma unroll
  for (int i=0;i<16;i++){
    int flat = i*256 + tid;
    int rr = flat >> 6, cc = flat & 63;
    int c = c0 + cc;
    tile[rr][cc] = (c < C) ? src[(size_t)(r0+rr)*C + c] : 0.f;
  }
  __syncthreads();
  #pragma unroll
  for (int i=0;i<16;i++){
    int flat = i*256 + tid;
    int cc = flat >> 6, rr = flat & 63;
    dst[(size_t)(c0+cc)*R + r0 + rr] = f2b(tile[rr][cc]);
  }
}
__global__ void k_wch(const float* __restrict__ wih, const float* __restrict__ whh, u16* __restrict__ o){
  int i = blockIdx.x*256 + threadIdx.x;
  if (i < G4*KX){
    int gp = i / KX, k = i % KX;
    int j = gp >> 2, gate = gp & 3, g = gate*H + j;
    float v = (k < H2) ? wih[(size_t)g*(E+H2) + E + k] : whh[(size_t)g*H + (k - H2)];
    o[i] = f2b(v);
  }
}
__global__ void k_wihe(const float* __restrict__ wih, u16* __restrict__ o){
  int i = blockIdx.x*256 + threadIdx.x;
  if (i < G4*E){
    int gp = i / E, e = i % E;
    int j = gp >> 2, gate = gp & 3, g = gate*H + j;
    o[i] = f2b(wih[(size_t)g*(E+H2) + e]);
  }
}
__global__ void k_bias(const float* __restrict__ bi, const float* __restrict__ bh, float* __restrict__ o){
  int i = blockIdx.x*256 + threadIdx.x;
  if (i < G4){
    int j = i >> 2, gate = i & 3, g = gate*H + j;
    o[i] = bi[g] + bh[g];
  }
}
__global__ void k_emb(const int* __restrict__ trg, const float* __restrict__ emb, u16* __restrict__ catp){
  int i = blockIdx.x*256 + threadIdx.x;
  if (i < NROW*E){
    int row = i >> 8, e = i & 255;
    int tok = trg[row];
    catp[(size_t)row*KP + e] = f2b(emb[(size_t)tok*E + e]);
  }
}
__global__ void k_init(const float* __restrict__ h0, u16* __restrict__ xgs){
  int i = blockIdx.x*256 + threadIdx.x;
  if (i < B*H){
    int b = i >> 9, j = i & 511;
    xgs[(size_t)b*KX + H2 + j] = f2b(h0[i]);   // slot 0 h-region
  }
}
__global__ void k_zero(unsigned* bar){
  int i = blockIdx.x*256 + threadIdx.x;
  if (i < BAR_WORDS) bar[i] = 0u;
}
__global__ void k_lse(const float* __restrict__ sep, float* __restrict__ lse){
  int r = blockIdx.x*256 + threadIdx.x;
  if (r < NROW){
    float s = 0.f;
    for (int i=0;i<79;i++) s += sep[(size_t)r*80 + i];
    lse[r] = logf(s);
  }
}

// ---------------- MFMA GEMM: C[row,col] = sum_k A[row,k]*BT[col,k] ----------------
template<int TN, int EPI>
__global__ __launch_bounds__(256) void gemm_bf16(
    const u16* __restrict__ A, int lda,
    const u16* __restrict__ BT, int ldb,
    int K,
    u16* outb, int ldc,
    float* sep,
    float* outp, const float* lse)
{
  constexpr int NSUB = TN/16;
  constexpr int NB = TN/64;
  __shared__ u16 sA[64*32];
  __shared__ u16 sB[TN*32];
  __shared__ float Cx[(EPI==3) ? 128*65 : 1];
  __shared__ float lseb[(EPI==3)?64:1];

  const int tid = threadIdx.x;
  const int lane = tid & 63;
  const int wv = tid >> 6;
  const int row0 = blockIdx.x * 64;
  const int n0 = blockIdx.y * TN;

  floatx4 acc[NSUB];
  #pragma unroll
  for (int s=0;s<NSUB;s++) acc[s] = (floatx4){0.f,0.f,0.f,0.f};

  const int ar = tid >> 2;
  const int ch = tid & 3;
  const int swz = (ar >> 1) & 3;
  const int px = ((lane & 15) >> 1) & 3;

  const u16* gA = A + (size_t)(row0+ar)*lda + ch*8;
  bf16x8 pa = *(const bf16x8*)gA;
  bf16x8 pb[NB];
  #pragma unroll
  for (int i=0;i<NB;i++) pb[i] = *(const bf16x8*)(BT + (size_t)(n0+i*64+ar)*ldb + ch*8);

  for (int k0 = 0; k0 < K; k0 += 32){
    __syncthreads();
    *(bf16x8*)&sA[ar*32 + ((ch ^ swz)*8)] = pa;
    #pragma unroll
    for (int i=0;i<NB;i++)
      *(bf16x8*)&sB[(i*64+ar)*32 + ((ch ^ swz)*8)] = pb[i];
    __syncthreads();
    if (k0 + 32 < K){
      pa = *(const bf16x8*)(gA + k0 + 32);
      #pragma unroll
      for (int i=0;i<NB;i++) pb[i] = *(const bf16x8*)(BT + (size_t)(n0+i*64+ar)*ldb + k0+32 + ch*8);
    }
    bf16x8 af = *(const bf16x8*)&sA[(16*wv + (lane&15))*32 + (((lane>>4) ^ px)*8)];
    #pragma unroll
    for (int s=0;s<NSUB;s++){
      bf16x8 bfv = *(const bf16x8*)&sB[(16*s + (lane&15))*32 + (((lane>>4) ^ px)*8)];
      acc[s] = __builtin_amdgcn_mfma_f32_16x16x32_bf16(af, bfv, acc[s], 0, 0, 0);
    }
  }

  if constexpr (EPI == 0 || EPI == 4){
    #pragma unroll
    for (int s=0;s<NSUB;s++)
      #pragma unroll
      for (int r=0;r<4;r++){
        int row = row0 + 16*wv + ((lane>>4)<<2) + r;
        int col = n0 + 16*s + (lane&15);
        if (EPI == 4) row = ((row & 63) << 6) | (row >> 6);   // b*T+t -> t*B+b
        outb[(size_t)row*ldc + col] = f2b(acc[s][r]);
      }
  }
  if constexpr (EPI == 2){
    float sr[4] = {0.f,0.f,0.f,0.f};
    #pragma unroll
    for (int s=0;s<NSUB;s++){
      int col = n0 + 16*s + (lane&15);
      if (col < V){
        #pragma unroll
        for (int r=0;r<4;r++) sr[r] += __expf(acc[s][r]);
      }
    }
    #pragma unroll
    for (int r=0;r<4;r++){
      float v = sr[r];
      v += __shfl_xor(v,1); v += __shfl_xor(v,2); v += __shfl_xor(v,4); v += __shfl_xor(v,8);
      sr[r] = v;
    }
    if ((lane&15)==0){
      #pragma unroll
      for (int r=0;r<4;r++){
        int row = row0 + 16*wv + ((lane>>4)<<2) + r;
        sep[(size_t)row*80 + blockIdx.y] = sr[r];
      }
    }
  }
  if constexpr (EPI == 3){
    #pragma unroll
    for (int s=0;s<NSUB;s++)
      #pragma unroll
      for (int r=0;r<4;r++){
        int rl = 16*wv + ((lane>>4)<<2) + r;
        int cl = 16*s + (lane&15);
        Cx[cl*65 + rl] = acc[s][r];
      }
    if (tid < 64) lseb[tid] = lse[row0 + tid];
    __syncthreads();
    int b = blockIdx.x;
    for (int idx = tid; idx < TN*16; idx += 256){
      int vl = idx >> 4, q4 = idx & 15;
      int v = n0 + vl;
      if (v < V){
        floatx4 o;
        o[0] = Cx[vl*65 + q4*4+0] - lseb[q4*4+0];
        o[1] = Cx[vl*65 + q4*4+1] - lseb[q4*4+1];
        o[2] = Cx[vl*65 + q4*4+2] - lseb[q4*4+2];
        o[3] = Cx[vl*65 + q4*4+3] - lseb[q4*4+3];
        *(floatx4*)&outp[((size_t)b*V + v)*T + q4*4] = o;
      }
    }
  }
}

// ---------------- direct producer->consumer flag wait ----------------
// 64 lanes gather-poll 64 producer lines (1 writer + 1 poll-lane per line, monotone gen).
__device__ __forceinline__ void wait_flags(unsigned* base, unsigned g){
  if (threadIdx.x < 64){
    unsigned* p = base + (unsigned)threadIdx.x*64;
    int it = 0;
    while (ld_if(p) < g && ++it < 5000000) asm volatile("s_sleep 1":::);
  }
  __syncthreads();
}

// ---------------- persistent recurrence: 128 blocks x 512 threads, flag handoffs ----------------
__global__ __launch_bounds__(512) void decoder_loop(
    u16* __restrict__ xgs, const float* __restrict__ c0f, float* __restrict__ outp,
    const u16* __restrict__ pk, const u16* __restrict__ encb,
    const float* __restrict__ we, const int* __restrict__ lens,
    const u16* __restrict__ wqT, u16* __restrict__ cph,
    const u16* __restrict__ wch, const u16* __restrict__ gembt,
    const float* __restrict__ bias, unsigned* __restrict__ bar)
{
  __shared__ u16 sA[64*128];
  __shared__ u16 sB[32*128];
  __shared__ float Cx[64*36];
  __shared__ u16 hsb[H];
  __shared__ __align__(16) float qw[H];
  __shared__ __align__(16) float wel[H];
  __shared__ float ep[512];
  __shared__ float ev[S], al[S];
  __shared__ float smax, sinv;

  const int tid = threadIdx.x, lane = tid & 63, wv = tid >> 6;
  const int blk = blockIdx.x;
  const int xcd = blk & 7, slot = blk >> 3;
  unsigned* flag_ctx = bar;            // [b]
  unsigned* flag_h   = bar + 64*64;    // [g]

  if (slot < 8){
    // ================= attention role (blocks 0..63) =================
    const int b = xcd*8 + slot;
    const int lenb = lens[b];
    wel[tid] = we[tid];
    __syncthreads();

    for (int t=0; t<T; t++){
      wait_flags(flag_h, (unsigned)t);
      u16* xgt = xgs + (size_t)t*B*KX;
      hsb[tid] = xgt[b*KX + H2 + tid];
      __syncthreads();
      // q = h @ Wquery via MFMA (broadcast-h A fragment)
      {
        floatx4 accq[4];
        #pragma unroll
        for (int s=0;s<4;s++) accq[s] = (floatx4){0.f,0.f,0.f,0.f};
        const int kc = (lane>>4)*8;
        #pragma unroll 4
        for (int ks=0; ks<16; ks++){
          bf16x8 af = *(const bf16x8*)&hsb[ks*32 + kc];
          #pragma unroll
          for (int s=0;s<4;s++){
            const u16* bp = wqT + (size_t)(wv*64 + s*16 + (lane&15))*H + ks*32 + kc;
            accq[s] = __builtin_amdgcn_mfma_f32_16x16x32_bf16(af, *(const bf16x8*)bp, accq[s], 0, 0, 0);
          }
        }
        if (lane < 16){
          #pragma unroll
          for (int s=0;s<4;s++) qw[wv*64 + s*16 + lane] = accq[s][0];
        }
      }
      __syncthreads();
      // energies (vectorized LDS reads; div-free tanh; skip s >= lenb)
      {
        int s = tid >> 2, part = tid & 3;
        float a0 = 0.f;
        if (s < lenb){
          const u16* pr = pk + (size_t)(b*S + s)*H;
          #pragma unroll 4
          for (int m=0;m<16;m++){
            int k0 = part*8 + m*32;
            bf16x8 p8 = *(const bf16x8*)(pr + k0);
            floatx4 qa = *(const floatx4*)&qw[k0];
            floatx4 qb = *(const floatx4*)&qw[k0+4];
            floatx4 wa = *(const floatx4*)&wel[k0];
            floatx4 wb = *(const floatx4*)&wel[k0+4];
            #pragma unroll
            for (int i=0;i<4;i++){
              a0 += tanh_fast(qa[i] + b2f((u16)p8[i]))   * wa[i];
              a0 += tanh_fast(qb[i] + b2f((u16)p8[i+4])) * wb[i];
            }
          }
        }
        ep[tid] = a0;
      }
      __syncthreads();
      if (tid < S){
        float e = ep[tid*4] + ep[tid*4+1] + ep[tid*4+2] + ep[tid*4+3];
        ev[tid] = (tid < lenb) ? e : -1e30f;
      }
      __syncthreads();
      if (tid < 64){
        float m = fmaxf(ev[tid], ev[tid+64]);
        #pragma unroll
        for (int o=32;o>=1;o>>=1) m = fmaxf(m, __shfl_xor(m,o));
        if (tid==0) smax = m;
      }
      __syncthreads();
      if (tid < S) al[tid] = __expf(ev[tid]-smax);
      __syncthreads();
      if (tid < 64){
        float s2 = al[tid] + al[tid+64];
        #pragma unroll
        for (int o=32;o>=1;o>>=1) s2 += __shfl_xor(s2,o);
        if (tid==0) sinv = rcpf(s2);
      }
      __syncthreads();
      // ctx (loop bound lenb; al==0 beyond -> exact)
      {
        float cx0=0.f, cx1=0.f;
        int d = tid*2;
        const u16* er = encb + (size_t)(b*S)*H2 + d;
        for (int ss=0; ss<lenb; ss++){
          unsigned int u = *(const unsigned int*)(er + (size_t)ss*H2);
          float a = al[ss];
          cx0 += a * b2f((u16)(u & 0xFFFFu));
          cx1 += a * b2f((u16)(u >> 16));
        }
        cx0 *= sinv; cx1 *= sinv;
        unsigned pack = ((unsigned)f2b(cx1) << 16) | (unsigned)f2b(cx0);
        st_wt_u32(xgt + (size_t)b*KX + d, pack);            // ctx -> slot t (gates read)
        *(unsigned*)&cph[(size_t)(b*T + t)*KP + E + H + d] = pack;  // normal store
      }
      // publish ctx(t): drain all waves' stores, then one flag store
      asm volatile("s_waitcnt vmcnt(0)" ::: "memory");
      __syncthreads();
      if (tid == 0) st_if(flag_ctx + (unsigned)b*64, (unsigned)(t+1));
      __syncthreads();
    }
  } else {
    // ================= gates role (blocks 64..127): C[64 x 32] K=1536, split-K 8 waves ==========
    const int g = slot - 8;
    const int gid = xcd*8 + g;                              // flag index 0..63
    const int n0 = xcd*256 + g*32;
    const int kh = wv >> 2, wr = wv & 3;
    const int rs0 = tid >> 4, gs = tid & 15;
    const int rowa = 16*wr + (lane & 15);
    const int pb_ = tid >> 3, jl = tid & 7;
    const int jglob = (n0 >> 2) + jl;
    float creg = c0f[pb_*H + jglob];                        // c state register-resident
    floatx4 bias4 = *(const floatx4*)(bias + n0 + jl*4);

    for (int t=0; t<T; t++){
      // wait for ctx(t): all 64 attn blocks have flag >= t+1
      wait_flags(flag_ctx, (unsigned)(t+1));
      const u16* xgt = xgs + (size_t)t*B*KX;
      u16* xgn = xgs + (size_t)(t+1)*B*KX;
      bf16x4 g4 = *(const bf16x4*)(gembt + (size_t)(t*B + pb_)*G4 + n0 + jl*4);

      floatx4 acc[2];
      acc[0] = (floatx4){0.f,0.f,0.f,0.f};
      acc[1] = (floatx4){0.f,0.f,0.f,0.f};
      bf16x8 a0 = *(const bf16x8*)(xgt + (size_t)rs0*KX + gs*8);
      bf16x8 a1 = *(const bf16x8*)(xgt + (size_t)(rs0+32)*KX + gs*8);
      bf16x8 b0 = *(const bf16x8*)(wch + (size_t)(n0+rs0)*KX + gs*8);

      for (int kk=0; kk<12; kk++){
        __syncthreads();
        *(bf16x8*)&sA[rs0*128 + ((gs ^ (rs0&7))*8)] = a0;
        *(bf16x8*)&sA[(rs0+32)*128 + ((gs ^ (rs0&7))*8)] = a1;
        *(bf16x8*)&sB[rs0*128 + ((gs ^ (rs0&7))*8)] = b0;
        __syncthreads();
        if (kk < 11){
          int ko = (kk+1)*128;
          a0 = *(const bf16x8*)(xgt + (size_t)rs0*KX + ko + gs*8);
          a1 = *(const bf16x8*)(xgt + (size_t)(rs0+32)*KX + ko + gs*8);
          b0 = *(const bf16x8*)(wch + (size_t)(n0+rs0)*KX + ko + gs*8);
        }
        #pragma unroll
        for (int ks=0; ks<2; ks++){
          int gq = kh*8 + ks*4 + (lane>>4);
          bf16x8 af = *(const bf16x8*)&sA[rowa*128 + ((gq ^ (rowa&7))*8)];
          #pragma unroll
          for (int s=0;s<2;s++){
            int rowb = 16*s + (lane & 15);
            bf16x8 bfv = *(const bf16x8*)&sB[rowb*128 + ((gq ^ (rowb&7))*8)];
            acc[s] = __builtin_amdgcn_mfma_f32_16x16x32_bf16(af, bfv, acc[s], 0, 0, 0);
          }
        }
      }
      {
        int r0 = 16*wr + ((lane>>4)<<2);
        if (kh == 1){
          #pragma unroll
          for (int s=0;s<2;s++)
            #pragma unroll
            for (int r=0;r<4;r++) Cx[(r0+r)*36 + 16*s + (lane&15)] = acc[s][r];
        }
      }
      __syncthreads();
      {
        int r0 = 16*wr + ((lane>>4)<<2);
        if (kh == 0){
          #pragma unroll
          for (int s=0;s<2;s++)
            #pragma unroll
            for (int r=0;r<4;r++) Cx[(r0+r)*36 + 16*s + (lane&15)] += acc[s][r];
        }
      }
      __syncthreads();
      // LSTM pointwise: thread owns (b=pb_, j=jglob)
      {
        float gi = Cx[pb_*36 + jl*4+0] + b2f((u16)g4[0]) + bias4[0];
        float gf = Cx[pb_*36 + jl*4+1] + b2f((u16)g4[1]) + bias4[1];
        float gg = Cx[pb_*36 + jl*4+2] + b2f((u16)g4[2]) + bias4[2];
        float go = Cx[pb_*36 + jl*4+3] + b2f((u16)g4[3]) + bias4[3];
        float cn = sigf(gf)*creg + sigf(gi)*tanhf(gg);
        float hn = sigf(go)*tanhf(cn);
        creg = cn;
        u16 hb = f2b(hn);
        st_wt_u16(xgn + (size_t)pb_*KX + H2 + jglob, (unsigned)hb);  // h -> slot t+1
        cph[(size_t)(pb_*T + t)*KP + E + jglob] = hb;                 // normal store
        if (t == T-1){
          outp[(size_t)B*V*T + pb_*H + jglob] = hn;
          outp[(size_t)B*V*T + B*H + pb_*H + jglob] = cn;
        }
      }
      // publish h(t+1)
      asm volatile("s_waitcnt vmcnt(0)" ::: "memory");
      __syncthreads();
      if (tid == 0) st_if(flag_h + (unsigned)gid*64, (unsigned)(t+1));
      __syncthreads();
    }
  }
}

static inline int cdiv(int a, int b){ return (a + b - 1) / b; }

extern "C" void kernel_launch(void* const* d_in, const int* in_sizes, int n_in,
                              void* d_out, int out_size, void* d_ws, size_t ws_size,
                              hipStream_t stream)
{
  (void)in_sizes; (void)n_in; (void)out_size; (void)ws_size;
  const int*   trg  = (const int*)d_in[0];
  const float* enc  = (const float*)d_in[1];
  const int*   lens = (const int*)d_in[2];
  const float* h0   = (const float*)d_in[3];
  const float* c0   = (const float*)d_in[4];
  const float* embt = (const float*)d_in[5];
  const float* wkey = (const float*)d_in[6];
  const float* wqry = (const float*)d_in[7];
  const float* we   = (const float*)d_in[8];
  const float* wih  = (const float*)d_in[9];
  const float* whh  = (const float*)d_in[10];
  const float* bi   = (const float*)d_in[11];
  const float* bh   = (const float*)d_in[12];
  const float* wpre = (const float*)d_in[13];
  const float* wgen = (const float*)d_in[14];
  float* out = (float*)d_out;

  char* p = (char*)d_ws;
  auto carve = [&](size_t bytes)->char*{ char* r = p; p += (bytes + 255) & ~(size_t)255; return r; };
  u16*   encb  = (u16*)  carve((size_t)B*S*H2*2);
  u16*   pkb   = (u16*)  carve((size_t)B*S*H*2);
  u16*   catp  = (u16*)  carve((size_t)NROW*KP*2);
  u16*   gembb = (u16*)  carve((size_t)NROW*G4*2);   // [t*B+b][G4]
  u16*   preb  = (u16*)  carve((size_t)NROW*H*2);
  u16*   wgt   = (u16*)  carve((size_t)VP*H*2);
  u16*   wch   = (u16*)  carve((size_t)G4*KX*2);
  u16*   wihe  = (u16*)  carve((size_t)G4*E*2);
  u16*   wkeyT = (u16*)  carve((size_t)H*H2*2);
  u16*   wqT   = (u16*)  carve((size_t)H*H*2);
  u16*   wpreT = (u16*)  carve((size_t)H*KP*2);
  u16*   xgs   = (u16*)  carve((size_t)(T+1)*B*KX*2);  // 65 fresh slots
  float* biasp = (float*)carve((size_t)G4*4);
  float* sep   = (float*)carve((size_t)NROW*80*4);
  float* lse   = (float*)carve((size_t)NROW*4);
  unsigned* bar = (unsigned*)carve(BAR_WORDS*4);

  // ---- prep ----
  k_cast<<<cdiv(B*S*H2,256),256,0,stream>>>(enc, encb, B*S*H2);
  k_tct<<<dim3(H/64, H/64),256,0,stream>>>(wqry, wqT, H, H);         // -> [H][H] (j,k)
  k_tct<<<dim3(H/64, H2/64),256,0,stream>>>(wkey, wkeyT, H2, H);     // -> [H][H2]
  k_tct<<<dim3(H/64, KP/64),256,0,stream>>>(wpre, wpreT, KP, H);     // -> [H][KP]
  k_tct<<<dim3(VP/64, H/64),256,0,stream>>>(wgen, wgt, H, V);        // -> [VP][H]
  k_wch<<<cdiv(G4*KX,256),256,0,stream>>>(wih, whh, wch);
  k_wihe<<<cdiv(G4*E,256),256,0,stream>>>(wih, wihe);
  k_bias<<<cdiv(G4,256),256,0,stream>>>(bi, bh, biasp);
  k_emb<<<cdiv(NROW*E,256),256,0,stream>>>(trg, embt, catp);
  k_init<<<cdiv(B*H,256),256,0,stream>>>(h0, xgs);
  k_zero<<<cdiv(BAR_WORDS,256),256,0,stream>>>(bar);

  // proj_key = enc @ Wkey  -> pk bf16 [B*S][H]
  gemm_bf16<64,0><<<dim3(B*S/64, H/64),256,0,stream>>>(
      encb, H2, wkeyT, H2, H2, pkb, H, nullptr, nullptr, nullptr);
  // Gemb = emb @ W_ih[:, :E].T (permuted cols), rows remapped to [t*B+b]
  gemm_bf16<64,4><<<dim3(NROW/64, G4/64),256,0,stream>>>(
      catp, KP, wihe, E, E, gembb, G4, nullptr, nullptr, nullptr);

  // ---- recurrence: one persistent kernel, flag-handoffs only ----
  decoder_loop<<<128,512,0,stream>>>(xgs, c0, out, pkb, encb, we, lens,
                                     wqT, catp, wch, gembb, biasp, bar);

  // pre = cat_pre @ Wpre -> bf16 [NROW][H]
  gemm_bf16<64,0><<<dim3(NROW/64, H/64),256,0,stream>>>(
      catp, KP, wpreT, KP, KP, preb, H, nullptr, nullptr, nullptr);

  // generator pass 1: sum-exp partials
  gemm_bf16<128,2><<<dim3(NROW/64, VP/128),256,0,stream>>>(
      preb, H, wgt, H, H, nullptr, 0, sep, nullptr, nullptr);
  k_lse<<<cdiv(NROW,256),256,0,stream>>>(sep, lse);
  // generator pass 2: write out[b][v][t] = logit - lse
  gemm_bf16<128,3><<<dim3(NROW/64, VP/128),256,0,stream>>>(
      preb, H, wgt, H, H, nullptr, 0, nullptr, out, lse);
}

// Round 18
// 2488.714 us; speedup vs baseline: 1.2625x; 1.0042x over previous
//
#include <hip/hip_runtime.h>

#define B 64
#define S 128
#define T 64
#define H 512
#define E 256
#define V 10000
#define H2 1024      // 2H
#define G4 2048      // 4H
#define KX 1536      // ctx(1024)+h(512) gate GEMM K
#define KP 1792      // E + H + 2H pre concat K
#define VP 10112     // padded V = 79*128
#define NROW 4096    // B*T

typedef unsigned short u16;
typedef __attribute__((ext_vector_type(8))) short bf16x8;
typedef __attribute__((ext_vector_type(4))) short bf16x4;
typedef __attribute__((ext_vector_type(4))) float floatx4;

__device__ inline float b2f(u16 h){
  union { unsigned int u; float f; } v; v.u = ((unsigned int)h) << 16; return v.f;
}
__device__ inline u16 f2b(float f){
  union { unsigned int u; float f; } v; v.f = f;
  unsigned int r = v.u + 0x7FFFu + ((v.u >> 16) & 1u);
  return (u16)(r >> 16);
}
__device__ __forceinline__ float rcpf(float x){ return __builtin_amdgcn_rcpf(x); }
__device__ inline float sigf(float x){ return rcpf(1.f + __expf(-x)); }
__device__ inline float tanh_fast(float x){ float e=__expf(2.f*x); return 1.f - 2.f*rcpf(e+1.f); }

// ---- IF$-coherent ops (sc0 sc1): the ONLY proven cross-CU-coherent path (R4/R6/R9; R7: sc0-only fails) ----
__device__ __forceinline__ void st_wt_u32(u16* p, unsigned v){
  asm volatile("global_store_dword %0, %1, off sc0 sc1" :: "v"(p), "v"(v) : "memory");
}
__device__ __forceinline__ void st_wt_u16(u16* p, unsigned v){
  asm volatile("global_store_short %0, %1, off sc0 sc1" :: "v"(p), "v"(v) : "memory");
}
__device__ __forceinline__ unsigned ld_if(unsigned* p){
  unsigned v;
  asm volatile("global_load_dword %0, %1, off sc0 sc1\ns_waitcnt vmcnt(0)" : "=v"(v) : "v"(p) : "memory");
  return v;
}
__device__ __forceinline__ void st_if(unsigned* p, unsigned v){
  asm volatile("global_store_dword %0, %1, off sc0 sc1\ns_waitcnt vmcnt(0)" :: "v"(p), "v"(v) : "memory");
}

// flag layout: flag_ctx[b] at bar+b*64, flag_h[g] at bar+(64+g)*64 (256B-spaced lines)
#define BAR_WORDS (128*64)

// ---------------- prep kernels ----------------
__global__ void k_cast(const float* __restrict__ src, u16* __restrict__ dst, int n){
  int i = blockIdx.x*256 + threadIdx.x;
  if (i < n) dst[i] = f2b(src[i]);
}
__global__ void k_tct(const float* __restrict__ src, u16* __restrict__ dst, int R, int C){
  __shared__ float tile[64][65];
  int c0 = blockIdx.x*64, r0 = blockIdx.y*64;
  int tid = threadIdx.x;
  #pragma unroll
  for (int i=0;i<16;i++){
    int flat = i*256 + tid;
    int rr = flat >> 6, cc = flat & 63;
    int c = c0 + cc;
    tile[rr][cc] = (c < C) ? src[(size_t)(r0+rr)*C + c] : 0.f;
  }
  __syncthreads();
  #pragma unroll
  for (int i=0;i<16;i++){
    int flat = i*256 + tid;
    int cc = flat >> 6, rr = flat & 63;
    dst[(size_t)(c0+cc)*R + r0 + rr] = f2b(tile[rr][cc]);
  }
}
__global__ void k_wch(const float* __restrict__ wih, const float* __restrict__ whh, u16* __restrict__ o){
  int i = blockIdx.x*256 + threadIdx.x;
  if (i < G4*KX){
    int gp = i / KX, k = i % KX;
    int j = gp >> 2, gate = gp & 3, g = gate*H + j;
    float v = (k < H2) ? wih[(size_t)g*(E+H2) + E + k] : whh[(size_t)g*H + (k - H2)];
    o[i] = f2b(v);
  }
}
__global__ void k_wihe(const float* __restrict__ wih, u16* __restrict__ o){
  int i = blockIdx.x*256 + threadIdx.x;
  if (i < G4*E){
    int gp = i / E, e = i % E;
    int j = gp >> 2, gate = gp & 3, g = gate*H + j;
    o[i] = f2b(wih[(size_t)g*(E+H2) + e]);
  }
}
__global__ void k_bias(const float* __restrict__ bi, const float* __restrict__ bh, float* __restrict__ o){
  int i = blockIdx.x*256 + threadIdx.x;
  if (i < G4){
    int j = i >> 2, gate = i & 3, g = gate*H + j;
    o[i] = bi[g] + bh[g];
  }
}
__global__ void k_emb(const int* __restrict__ trg, const float* __restrict__ emb, u16* __restrict__ catp){
  int i = blockIdx.x*256 + threadIdx.x;
  if (i < NROW*E){
    int row = i >> 8, e = i & 255;
    int tok = trg[row];
    catp[(size_t)row*KP + e] = f2b(emb[(size_t)tok*E + e]);
  }
}
__global__ void k_init(const float* __restrict__ h0, u16* __restrict__ xgs){
  int i = blockIdx.x*256 + threadIdx.x;
  if (i < B*H){
    int b = i >> 9, j = i & 511;
    xgs[(size_t)b*KX + H2 + j] = f2b(h0[i]);   // slot 0 h-region
  }
}
__global__ void k_zero(unsigned* bar){
  int i = blockIdx.x*256 + threadIdx.x;
  if (i < BAR_WORDS) bar[i] = 0u;
}
__global__ void k_lse(const float* __restrict__ sep, float* __restrict__ lse){
  int r = blockIdx.x*256 + threadIdx.x;
  if (r < NROW){
    float s = 0.f;
    for (int i=0;i<79;i++) s += sep[(size_t)r*80 + i];
    lse[r] = logf(s);
  }
}
// out[(b*V+v)*T+t] -= lse[b*T+t], float4-vectorized (t stride 1, T=64 so t%4==0 at f%4==0)
__global__ void k_fix(float* __restrict__ out, const float* __restrict__ lse){
  size_t i = (size_t)blockIdx.x*256 + threadIdx.x;
  size_t f = i*4;
  if (f < (size_t)B*V*T){
    int t = (int)(f & 63);
    int bv = (int)(f >> 6);
    int b = bv / V;
    floatx4 o = *(floatx4*)&out[f];
    floatx4 l = *(const floatx4*)&lse[b*T + t];
    o[0] -= l[0]; o[1] -= l[1]; o[2] -= l[2]; o[3] -= l[3];
    *(floatx4*)&out[f] = o;
  }
}

// ---------------- MFMA GEMM: C[row,col] = sum_k A[row,k]*BT[col,k] ----------------
// EPI 0: store bf16. EPI 4: store bf16 with row remap (b*T+t -> t*B+b).
// EPI 5: sum-exp partials + transposed raw-logit store to out[b][v][t].
template<int TN, int EPI>
__global__ __launch_bounds__(256) void gemm_bf16(
    const u16* __restrict__ A, int lda,
    const u16* __restrict__ BT, int ldb,
    int K,
    u16* outb, int ldc,
    float* sep,
    float* outp, const float* lse)
{
  constexpr int NSUB = TN/16;
  constexpr int NB = TN/64;
  __shared__ u16 sA[64*32];
  __shared__ u16 sB[TN*32];
  __shared__ float Cx[(EPI==5) ? 128*65 : 1];

  const int tid = threadIdx.x;
  const int lane = tid & 63;
  const int wv = tid >> 6;
  const int row0 = blockIdx.x * 64;
  const int n0 = blockIdx.y * TN;

  floatx4 acc[NSUB];
  #pragma unroll
  for (int s=0;s<NSUB;s++) acc[s] = (floatx4){0.f,0.f,0.f,0.f};

  const int ar = tid >> 2;
  const int ch = tid & 3;
  const int swz = (ar >> 1) & 3;
  const int px = ((lane & 15) >> 1) & 3;

  const u16* gA = A + (size_t)(row0+ar)*lda + ch*8;
  bf16x8 pa = *(const bf16x8*)gA;
  bf16x8 pb[NB];
  #pragma unroll
  for (int i=0;i<NB;i++) pb[i] = *(const bf16x8*)(BT + (size_t)(n0+i*64+ar)*ldb + ch*8);

  for (int k0 = 0; k0 < K; k0 += 32){
    __syncthreads();
    *(bf16x8*)&sA[ar*32 + ((ch ^ swz)*8)] = pa;
    #pragma unroll
    for (int i=0;i<NB;i++)
      *(bf16x8*)&sB[(i*64+ar)*32 + ((ch ^ swz)*8)] = pb[i];
    __syncthreads();
    if (k0 + 32 < K){
      pa = *(const bf16x8*)(gA + k0 + 32);
      #pragma unroll
      for (int i=0;i<NB;i++) pb[i] = *(const bf16x8*)(BT + (size_t)(n0+i*64+ar)*ldb + k0+32 + ch*8);
    }
    bf16x8 af = *(const bf16x8*)&sA[(16*wv + (lane&15))*32 + (((lane>>4) ^ px)*8)];
    #pragma unroll
    for (int s=0;s<NSUB;s++){
      bf16x8 bfv = *(const bf16x8*)&sB[(16*s + (lane&15))*32 + (((lane>>4) ^ px)*8)];
      acc[s] = __builtin_amdgcn_mfma_f32_16x16x32_bf16(af, bfv, acc[s], 0, 0, 0);
    }
  }

  if constexpr (EPI == 0 || EPI == 4){
    #pragma unroll
    for (int s=0;s<NSUB;s++)
      #pragma unroll
      for (int r=0;r<4;r++){
        int row = row0 + 16*wv + ((lane>>4)<<2) + r;
        int col = n0 + 16*s + (lane&15);
        if (EPI == 4) row = ((row & 63) << 6) | (row >> 6);   // b*T+t -> t*B+b
        outb[(size_t)row*ldc + col] = f2b(acc[s][r]);
      }
  }
  if constexpr (EPI == 5){
    // sum-exp partials (guard col < V; padded cols are garbage but excluded)
    {
      float sr[4] = {0.f,0.f,0.f,0.f};
      #pragma unroll
      for (int s=0;s<NSUB;s++){
        int col = n0 + 16*s + (lane&15);
        if (col < V){
          #pragma unroll
          for (int r=0;r<4;r++) sr[r] += __expf(acc[s][r]);
        }
      }
      #pragma unroll
      for (int r=0;r<4;r++){
        float v = sr[r];
        v += __shfl_xor(v,1); v += __shfl_xor(v,2); v += __shfl_xor(v,4); v += __shfl_xor(v,8);
        sr[r] = v;
      }
      if ((lane&15)==0){
        #pragma unroll
        for (int r=0;r<4;r++){
          int row = row0 + 16*wv + ((lane>>4)<<2) + r;
          sep[(size_t)row*80 + blockIdx.y] = sr[r];
        }
      }
    }
    // transpose in LDS and store RAW logits to out[b][v][t] (lse subtracted later by k_fix)
    #pragma unroll
    for (int s=0;s<NSUB;s++)
      #pragma unroll
      for (int r=0;r<4;r++){
        int rl = 16*wv + ((lane>>4)<<2) + r;   // t within row-block (block covers one b)
        int cl = 16*s + (lane&15);             // v local
        Cx[cl*65 + rl] = acc[s][r];
      }
    __syncthreads();
    int b = blockIdx.x;
    for (int idx = tid; idx < TN*16; idx += 256){
      int vl = idx >> 4, q4 = idx & 15;
      int v = n0 + vl;
      if (v < V){
        floatx4 o;
        o[0] = Cx[vl*65 + q4*4+0];
        o[1] = Cx[vl*65 + q4*4+1];
        o[2] = Cx[vl*65 + q4*4+2];
        o[3] = Cx[vl*65 + q4*4+3];
        *(floatx4*)&outp[((size_t)b*V + v)*T + q4*4] = o;
      }
    }
  }
}

// ---------------- direct producer->consumer flag wait ----------------
// 64 lanes gather-poll 64 producer lines (1 writer + 1 poll-lane per line, monotone gen).
__device__ __forceinline__ void wait_flags(unsigned* base, unsigned g){
  if (threadIdx.x < 64){
    unsigned* p = base + (unsigned)threadIdx.x*64;
    int it = 0;
    while (ld_if(p) < g && ++it < 5000000) asm volatile("s_sleep 1":::);
  }
  __syncthreads();
}

// ---------------- persistent recurrence: 128 blocks x 512 threads, flag handoffs ----------------
__global__ __launch_bounds__(512) void decoder_loop(
    u16* __restrict__ xgs, const float* __restrict__ c0f, float* __restrict__ outp,
    const u16* __restrict__ pk, const u16* __restrict__ encb,
    const float* __restrict__ we, const int* __restrict__ lens,
    const u16* __restrict__ wqT, u16* __restrict__ cph,
    const u16* __restrict__ wch, const u16* __restrict__ gembt,
    const float* __restrict__ bias, unsigned* __restrict__ bar)
{
  __shared__ u16 sA[64*128];
  __shared__ u16 sB[32*128];
  __shared__ float Cx[64*36];
  __shared__ u16 hsb[H];
  __shared__ __align__(16) float qw[H];
  __shared__ __align__(16) float wel[H];
  __shared__ float ep[512];
  __shared__ float ev[S], al[S];
  __shared__ float smax, sinv;

  const int tid = threadIdx.x, lane = tid & 63, wv = tid >> 6;
  const int blk = blockIdx.x;
  const int xcd = blk & 7, slot = blk >> 3;
  unsigned* flag_ctx = bar;            // [b]
  unsigned* flag_h   = bar + 64*64;    // [g]

  if (slot < 8){
    // ================= attention role (blocks 0..63) =================
    const int b = xcd*8 + slot;
    const int lenb = lens[b];
    wel[tid] = we[tid];
    __syncthreads();

    for (int t=0; t<T; t++){
      wait_flags(flag_h, (unsigned)t);
      u16* xgt = xgs + (size_t)t*B*KX;
      hsb[tid] = xgt[b*KX + H2 + tid];
      __syncthreads();
      // q = h @ Wquery via MFMA (broadcast-h A fragment)
      {
        floatx4 accq[4];
        #pragma unroll
        for (int s=0;s<4;s++) accq[s] = (floatx4){0.f,0.f,0.f,0.f};
        const int kc = (lane>>4)*8;
        #pragma unroll 4
        for (int ks=0; ks<16; ks++){
          bf16x8 af = *(const bf16x8*)&hsb[ks*32 + kc];
          #pragma unroll
          for (int s=0;s<4;s++){
            const u16* bp = wqT + (size_t)(wv*64 + s*16 + (lane&15))*H + ks*32 + kc;
            accq[s] = __builtin_amdgcn_mfma_f32_16x16x32_bf16(af, *(const bf16x8*)bp, accq[s], 0, 0, 0);
          }
        }
        if (lane < 16){
          #pragma unroll
          for (int s=0;s<4;s++) qw[wv*64 + s*16 + lane] = accq[s][0];
        }
      }
      __syncthreads();
      // energies (vectorized LDS reads; div-free tanh; skip s >= lenb)
      {
        int s = tid >> 2, part = tid & 3;
        float a0 = 0.f;
        if (s < lenb){
          const u16* pr = pk + (size_t)(b*S + s)*H;
          #pragma unroll 4
          for (int m=0;m<16;m++){
            int k0 = part*8 + m*32;
            bf16x8 p8 = *(const bf16x8*)(pr + k0);
            floatx4 qa = *(const floatx4*)&qw[k0];
            floatx4 qb = *(const floatx4*)&qw[k0+4];
            floatx4 wa = *(const floatx4*)&wel[k0];
            floatx4 wb = *(const floatx4*)&wel[k0+4];
            #pragma unroll
            for (int i=0;i<4;i++){
              a0 += tanh_fast(qa[i] + b2f((u16)p8[i]))   * wa[i];
              a0 += tanh_fast(qb[i] + b2f((u16)p8[i+4])) * wb[i];
            }
          }
        }
        ep[tid] = a0;
      }
      __syncthreads();
      if (tid < S){
        float e = ep[tid*4] + ep[tid*4+1] + ep[tid*4+2] + ep[tid*4+3];
        ev[tid] = (tid < lenb) ? e : -1e30f;
      }
      __syncthreads();
      if (tid < 64){
        float m = fmaxf(ev[tid], ev[tid+64]);
        #pragma unroll
        for (int o=32;o>=1;o>>=1) m = fmaxf(m, __shfl_xor(m,o));
        if (tid==0) smax = m;
      }
      __syncthreads();
      if (tid < S) al[tid] = __expf(ev[tid]-smax);
      __syncthreads();
      if (tid < 64){
        float s2 = al[tid] + al[tid+64];
        #pragma unroll
        for (int o=32;o>=1;o>>=1) s2 += __shfl_xor(s2,o);
        if (tid==0) sinv = rcpf(s2);
      }
      __syncthreads();
      // ctx (loop bound lenb; al==0 beyond -> exact)
      {
        float cx0=0.f, cx1=0.f;
        int d = tid*2;
        const u16* er = encb + (size_t)(b*S)*H2 + d;
        for (int ss=0; ss<lenb; ss++){
          unsigned int u = *(const unsigned int*)(er + (size_t)ss*H2);
          float a = al[ss];
          cx0 += a * b2f((u16)(u & 0xFFFFu));
          cx1 += a * b2f((u16)(u >> 16));
        }
        cx0 *= sinv; cx1 *= sinv;
        unsigned pack = ((unsigned)f2b(cx1) << 16) | (unsigned)f2b(cx0);
        st_wt_u32(xgt + (size_t)b*KX + d, pack);            // ctx -> slot t (gates read)
        *(unsigned*)&cph[(size_t)(b*T + t)*KP + E + H + d] = pack;  // normal store
      }
      // publish ctx(t): drain all waves' stores, then one flag store
      asm volatile("s_waitcnt vmcnt(0)" ::: "memory");
      __syncthreads();
      if (tid == 0) st_if(flag_ctx + (unsigned)b*64, (unsigned)(t+1));
      __syncthreads();
    }
  } else {
    // ================= gates role (blocks 64..127): C[64 x 32] K=1536, split-K 8 waves ==========
    const int g = slot - 8;
    const int gid = xcd*8 + g;                              // flag index 0..63
    const int n0 = xcd*256 + g*32;
    const int kh = wv >> 2, wr = wv & 3;
    const int rs0 = tid >> 4, gs = tid & 15;
    const int rowa = 16*wr + (lane & 15);
    const int pb_ = tid >> 3, jl = tid & 7;
    const int jglob = (n0 >> 2) + jl;
    float creg = c0f[pb_*H + jglob];                        // c state register-resident
    floatx4 bias4 = *(const floatx4*)(bias + n0 + jl*4);

    for (int t=0; t<T; t++){
      // wait for ctx(t): all 64 attn blocks have flag >= t+1
      wait_flags(flag_ctx, (unsigned)(t+1));
      const u16* xgt = xgs + (size_t)t*B*KX;
      u16* xgn = xgs + (size_t)(t+1)*B*KX;
      bf16x4 g4 = *(const bf16x4*)(gembt + (size_t)(t*B + pb_)*G4 + n0 + jl*4);

      floatx4 acc[2];
      acc[0] = (floatx4){0.f,0.f,0.f,0.f};
      acc[1] = (floatx4){0.f,0.f,0.f,0.f};
      bf16x8 a0 = *(const bf16x8*)(xgt + (size_t)rs0*KX + gs*8);
      bf16x8 a1 = *(const bf16x8*)(xgt + (size_t)(rs0+32)*KX + gs*8);
      bf16x8 b0 = *(const bf16x8*)(wch + (size_t)(n0+rs0)*KX + gs*8);

      for (int kk=0; kk<12; kk++){
        __syncthreads();
        *(bf16x8*)&sA[rs0*128 + ((gs ^ (rs0&7))*8)] = a0;
        *(bf16x8*)&sA[(rs0+32)*128 + ((gs ^ (rs0&7))*8)] = a1;
        *(bf16x8*)&sB[rs0*128 + ((gs ^ (rs0&7))*8)] = b0;
        __syncthreads();
        if (kk < 11){
          int ko = (kk+1)*128;
          a0 = *(const bf16x8*)(xgt + (size_t)rs0*KX + ko + gs*8);
          a1 = *(const bf16x8*)(xgt + (size_t)(rs0+32)*KX + ko + gs*8);
          b0 = *(const bf16x8*)(wch + (size_t)(n0+rs0)*KX + ko + gs*8);
        }
        #pragma unroll
        for (int ks=0; ks<2; ks++){
          int gq = kh*8 + ks*4 + (lane>>4);
          bf16x8 af = *(const bf16x8*)&sA[rowa*128 + ((gq ^ (rowa&7))*8)];
          #pragma unroll
          for (int s=0;s<2;s++){
            int rowb = 16*s + (lane & 15);
            bf16x8 bfv = *(const bf16x8*)&sB[rowb*128 + ((gq ^ (rowb&7))*8)];
            acc[s] = __builtin_amdgcn_mfma_f32_16x16x32_bf16(af, bfv, acc[s], 0, 0, 0);
          }
        }
      }
      {
        int r0 = 16*wr + ((lane>>4)<<2);
        if (kh == 1){
          #pragma unroll
          for (int s=0;s<2;s++)
            #pragma unroll
            for (int r=0;r<4;r++) Cx[(r0+r)*36 + 16*s + (lane&15)] = acc[s][r];
        }
      }
      __syncthreads();
      {
        int r0 = 16*wr + ((lane>>4)<<2);
        if (kh == 0){
          #pragma unroll
          for (int s=0;s<2;s++)
            #pragma unroll
            for (int r=0;r<4;r++) Cx[(r0+r)*36 + 16*s + (lane&15)] += acc[s][r];
        }
      }
      __syncthreads();
      // LSTM pointwise: thread owns (b=pb_, j=jglob)
      {
        float gi = Cx[pb_*36 + jl*4+0] + b2f((u16)g4[0]) + bias4[0];
        float gf = Cx[pb_*36 + jl*4+1] + b2f((u16)g4[1]) + bias4[1];
        float gg = Cx[pb_*36 + jl*4+2] + b2f((u16)g4[2]) + bias4[2];
        float go = Cx[pb_*36 + jl*4+3] + b2f((u16)g4[3]) + bias4[3];
        float cn = sigf(gf)*creg + sigf(gi)*tanhf(gg);
        float hn = sigf(go)*tanhf(cn);
        creg = cn;
        u16 hb = f2b(hn);
        st_wt_u16(xgn + (size_t)pb_*KX + H2 + jglob, (unsigned)hb);  // h -> slot t+1
        cph[(size_t)(pb_*T + t)*KP + E + jglob] = hb;                 // normal store
        if (t == T-1){
          outp[(size_t)B*V*T + pb_*H + jglob] = hn;
          outp[(size_t)B*V*T + B*H + pb_*H + jglob] = cn;
        }
      }
      // publish h(t+1)
      asm volatile("s_waitcnt vmcnt(0)" ::: "memory");
      __syncthreads();
      if (tid == 0) st_if(flag_h + (unsigned)gid*64, (unsigned)(t+1));
      __syncthreads();
    }
  }
}

static inline int cdiv(int a, int b){ return (a + b - 1) / b; }

extern "C" void kernel_launch(void* const* d_in, const int* in_sizes, int n_in,
                              void* d_out, int out_size, void* d_ws, size_t ws_size,
                              hipStream_t stream)
{
  (void)in_sizes; (void)n_in; (void)out_size; (void)ws_size;
  const int*   trg  = (const int*)d_in[0];
  const float* enc  = (const float*)d_in[1];
  const int*   lens = (const int*)d_in[2];
  const float* h0   = (const float*)d_in[3];
  const float* c0   = (const float*)d_in[4];
  const float* embt = (const float*)d_in[5];
  const float* wkey = (const float*)d_in[6];
  const float* wqry = (const float*)d_in[7];
  const float* we   = (const float*)d_in[8];
  const float* wih  = (const float*)d_in[9];
  const float* whh  = (const float*)d_in[10];
  const float* bi   = (const float*)d_in[11];
  const float* bh   = (const float*)d_in[12];
  const float* wpre = (const float*)d_in[13];
  const float* wgen = (const float*)d_in[14];
  float* out = (float*)d_out;

  char* p = (char*)d_ws;
  auto carve = [&](size_t bytes)->char*{ char* r = p; p += (bytes + 255) & ~(size_t)255; return r; };
  u16*   encb  = (u16*)  carve((size_t)B*S*H2*2);
  u16*   pkb   = (u16*)  carve((size_t)B*S*H*2);
  u16*   catp  = (u16*)  carve((size_t)NROW*KP*2);
  u16*   gembb = (u16*)  carve((size_t)NROW*G4*2);   // [t*B+b][G4]
  u16*   preb  = (u16*)  carve((size_t)NROW*H*2);
  u16*   wgt   = (u16*)  carve((size_t)VP*H*2);
  u16*   wch   = (u16*)  carve((size_t)G4*KX*2);
  u16*   wihe  = (u16*)  carve((size_t)G4*E*2);
  u16*   wkeyT = (u16*)  carve((size_t)H*H2*2);
  u16*   wqT   = (u16*)  carve((size_t)H*H*2);
  u16*   wpreT = (u16*)  carve((size_t)H*KP*2);
  u16*   xgs   = (u16*)  carve((size_t)(T+1)*B*KX*2);  // 65 fresh slots
  float* biasp = (float*)carve((size_t)G4*4);
  float* sep   = (float*)carve((size_t)NROW*80*4);
  float* lse   = (float*)carve((size_t)NROW*4);
  unsigned* bar = (unsigned*)carve(BAR_WORDS*4);

  // ---- prep ----
  k_cast<<<cdiv(B*S*H2,256),256,0,stream>>>(enc, encb, B*S*H2);
  k_tct<<<dim3(H/64, H/64),256,0,stream>>>(wqry, wqT, H, H);         // -> [H][H] (j,k)
  k_tct<<<dim3(H/64, H2/64),256,0,stream>>>(wkey, wkeyT, H2, H);     // -> [H][H2]
  k_tct<<<dim3(H/64, KP/64),256,0,stream>>>(wpre, wpreT, KP, H);     // -> [H][KP]
  k_tct<<<dim3(VP/64, H/64),256,0,stream>>>(wgen, wgt, H, V);        // -> [VP][H]
  k_wch<<<cdiv(G4*KX,256),256,0,stream>>>(wih, whh, wch);
  k_wihe<<<cdiv(G4*E,256),256,0,stream>>>(wih, wihe);
  k_bias<<<cdiv(G4,256),256,0,stream>>>(bi, bh, biasp);
  k_emb<<<cdiv(NROW*E,256),256,0,stream>>>(trg, embt, catp);
  k_init<<<cdiv(B*H,256),256,0,stream>>>(h0, xgs);
  k_zero<<<cdiv(BAR_WORDS,256),256,0,stream>>>(bar);

  // proj_key = enc @ Wkey  -> pk bf16 [B*S][H]
  gemm_bf16<64,0><<<dim3(B*S/64, H/64),256,0,stream>>>(
      encb, H2, wkeyT, H2, H2, pkb, H, nullptr, nullptr, nullptr);
  // Gemb = emb @ W_ih[:, :E].T (permuted cols), rows remapped to [t*B+b]
  gemm_bf16<64,4><<<dim3(NROW/64, G4/64),256,0,stream>>>(
      catp, KP, wihe, E, E, gembb, G4, nullptr, nullptr, nullptr);

  // ---- recurrence: one persistent kernel, flag-handoffs only ----
  decoder_loop<<<128,512,0,stream>>>(xgs, c0, out, pkb, encb, we, lens,
                                     wqT, catp, wch, gembb, biasp, bar);

  // pre = cat_pre @ Wpre -> bf16 [NROW][H]
  gemm_bf16<64,0><<<dim3(NROW/64, H/64),256,0,stream>>>(
      catp, KP, wpreT, KP, KP, preb, H, nullptr, nullptr, nullptr);

  // generator single pass: raw logits to out[b][v][t] + sum-exp partials
  gemm_bf16<128,5><<<dim3(NROW/64, VP/128),256,0,stream>>>(
      preb, H, wgt, H, H, nullptr, 0, sep, out, nullptr);
  k_lse<<<cdiv(NROW,256),256,0,stream>>>(sep, lse);
  // fixup: out -= lse (streaming, fully coalesced)
  k_fix<<<cdiv(B*V*T/4,256),256,0,stream>>>(out, lse);
}